// Round 12
// baseline (625.406 us; speedup 1.0000x reference)
//
#include <hip/hip_runtime.h>

#define HIGH 384
#define LOWD 64
#define EMB  128
#define HID  128

// Binned CSR build: bin = dst >> 8. Requires N <= 131072 (src packs in 17 bits).
#define BINSHIFT 8
#define SRCBITS  17
#define SRCMASK  0x1FFFF
#define NBLK     256

typedef unsigned int u32;
typedef unsigned short u16;
typedef unsigned char u8;
typedef __attribute__((ext_vector_type(8))) short bf16x8;
typedef __attribute__((ext_vector_type(4))) float f32x4;
typedef __attribute__((ext_vector_type(2))) float f32x2;

__device__ __forceinline__ u32 pack_bf16(float a, float b) {
    u32 ua = __builtin_bit_cast(u32, a);
    u32 ub = __builtin_bit_cast(u32, b);
    ua += 0x7fffu + ((ua >> 16) & 1u);
    ub += 0x7fffu + ((ub >> 16) & 1u);
    return (ua >> 16) | (ub & 0xffff0000u);
}
__device__ __forceinline__ u16 pack1_bf16(float a) {
    u32 ua = __builtin_bit_cast(u32, a);
    ua += 0x7fffu + ((ua >> 16) & 1u);
    return (u16)(ua >> 16);
}
__device__ __forceinline__ u8 pack1_fp8(float a) {
    int r = __builtin_amdgcn_cvt_pk_fp8_f32(a, a, 0, false);
    return (u8)(r & 0xff);
}

// ---------------- utility kernels ----------------

// All three weights: W[K][128] fp32 -> Wt[128][K] bf16
__global__ void k_castw_all(const float* __restrict__ W1, u16* __restrict__ Wt1,
                            const float* __restrict__ W2, u16* __restrict__ Wt2,
                            const float* __restrict__ WE, u16* __restrict__ WtE) {
    int i = blockIdx.x * 256 + threadIdx.x;
    if (i < 65536) {                       // W1: K=512
        int k = i >> 7, c = i & 127;
        Wt1[c * 512 + k] = pack1_bf16(W1[i]);
    } else if (i < 81920) {                // W2: K=128
        int j = i - 65536;
        int k = j >> 7, c = j & 127;
        Wt2[c * 128 + k] = pack1_bf16(W2[j]);
    } else if (i < 90112) {                // W_emb: K=64
        int j = i - 81920;
        int k = j >> 7, c = j & 127;
        WtE[c * 64 + k] = pack1_bf16(WE[j]);
    }
}

// ---------------- binned edge partition ----------------

__global__ __launch_bounds__(256) void k_binhist(const int* __restrict__ dst, int E,
                                                 int* __restrict__ cnts, int NB) {
    __shared__ int hist[512];
    for (int b = threadIdx.x; b < NB; b += 256) hist[b] = 0;
    __syncthreads();
    int CH = (E + gridDim.x - 1) / gridDim.x;
    int e0 = blockIdx.x * CH;
    int e1 = min(E, e0 + CH);
    for (int e = e0 + threadIdx.x; e < e1; e += 256)
        atomicAdd(&hist[dst[e] >> BINSHIFT], 1);
    __syncthreads();
    for (int b = threadIdx.x; b < NB; b += 256)
        cnts[b * NBLK + blockIdx.x] = hist[b];
}

__global__ __launch_bounds__(256) void k_binscatter(const int* __restrict__ src,
                                                    const int* __restrict__ dst, int E,
                                                    const int* __restrict__ cnts,
                                                    u32* __restrict__ packed, int NB) {
    __shared__ int cur[512];
    for (int b = threadIdx.x; b < NB; b += 256) cur[b] = cnts[b * NBLK + blockIdx.x];
    __syncthreads();
    int CH = (E + gridDim.x - 1) / gridDim.x;
    int e0 = blockIdx.x * CH;
    int e1 = min(E, e0 + CH);
    for (int e = e0 + threadIdx.x; e < e1; e += 256) {
        int d = dst[e];
        int s = src[e];
        int bin = d >> BINSHIFT;
        int pos = atomicAdd(&cur[bin], 1);
        packed[pos] = (u32)s | ((u32)(d & 255) << SRCBITS);
    }
}

// Fused per-bin CSR finalize: degree hist -> prefix -> row_start + dis -> csr fill.
__global__ __launch_bounds__(256) void k_csrbin(
    const u32* __restrict__ packed, const int* __restrict__ cnts, int E,
    int* __restrict__ row_start, float* __restrict__ dis,
    int* __restrict__ csr, int NB, int N)
{
    __shared__ int hist[256];
    __shared__ int sc[256];
    int t = threadIdx.x;
    int b = blockIdx.x;
    int begin = cnts[b * NBLK];
    int end = (b + 1 < NB) ? cnts[(b + 1) * NBLK] : E;

    hist[t] = 0;
    __syncthreads();
    for (int e = begin + t; e < end; e += 256)
        atomicAdd(&hist[packed[e] >> SRCBITS], 1);
    __syncthreads();
    int deg = hist[t];

    sc[t] = deg;
    __syncthreads();
    int x = deg;
    for (int off = 1; off < 256; off <<= 1) {
        int y = (t >= off) ? sc[t - off] : 0;
        __syncthreads();
        x += y; sc[t] = x;
        __syncthreads();
    }
    int rs = begin + (x - deg);

    int node = (b << BINSHIFT) + t;
    if (node < N) {
        row_start[node] = rs;
        dis[node] = rsqrtf((float)deg + 1.0f);
    }
    if (b == NB - 1 && t == 0) row_start[N] = E;

    hist[t] = rs;
    __syncthreads();
    for (int e = begin + t; e < end; e += 256) {
        u32 p = packed[e];
        int pos = atomicAdd(&hist[p >> SRCBITS], 1);
        csr[pos] = (int)((p & SRCMASK) << 5);
    }
}

// ---------------- scan (3-kernel, for cnts only) ----------------

__global__ void k_scan1(const int* __restrict__ in, int n, int* __restrict__ bsums) {
    __shared__ int sh[256];
    int t = threadIdx.x;
    int base = blockIdx.x * 1024 + t * 4;
    int s = 0;
#pragma unroll
    for (int j = 0; j < 4; j++) { int idx = base + j; s += (idx < n) ? in[idx] : 0; }
    sh[t] = s; __syncthreads();
    for (int off = 128; off > 0; off >>= 1) {
        if (t < off) sh[t] += sh[t + off];
        __syncthreads();
    }
    if (t == 0) bsums[blockIdx.x] = sh[0];
}

__global__ void k_scan2(int* bsums, int nb) {
    if (threadIdx.x == 0 && blockIdx.x == 0) {
        int run = 0;
        for (int i = 0; i < nb; i++) { int v = bsums[i]; bsums[i] = run; run += v; }
    }
}

__global__ void k_scan3_flat(int* __restrict__ data, int n, const int* __restrict__ bsums) {
    __shared__ int sh[256];
    int t = threadIdx.x;
    int base = blockIdx.x * 1024 + t * 4;
    int v[4]; int s = 0;
#pragma unroll
    for (int j = 0; j < 4; j++) { int idx = base + j; v[j] = (idx < n) ? data[idx] : 0; s += v[j]; }
    sh[t] = s; __syncthreads();
    int x = s;
    for (int off = 1; off < 256; off <<= 1) {
        int y = (t >= off) ? sh[t - off] : 0;
        __syncthreads();
        x += y; sh[t] = x;
        __syncthreads();
    }
    int run = bsums[blockIdx.x] + (x - s);
#pragma unroll
    for (int j = 0; j < 4; j++) {
        int idx = base + j;
        if (idx < n) data[idx] = run;
        run += v[j];
    }
}

// ---------------- persistent-W MFMA GEMM: C[M x 128] = [A1|A2] @ W ----------------
// 256 blocks x 768 threads (12 waves). W^T (bf16, [128 cols][K]) staged ONCE into LDS
// (chunk-XOR swizzle phys = ch ^ (c&7) -> 2-way-max bank conflicts on b128 reads).
// Each wave independently owns a 32x128 row-tile (grid-stride over row-tiles):
// NO barriers in the hot loop. A-frags load directly from global: lane l covers
// rows (l&15) and 16+(l&15), k-octet l>>4 -> each instr consumes 16 full 128B lines.
// Depth-2 register prefetch (pkA/pkB, static indices). OUT: 0 = bf16, 1 = fp8.

template<int K1, int K2, bool A1BF, bool BIAS, bool RELU, bool SCALE, int OUT>
__global__ __launch_bounds__(768, 1) void k_pgemm(
    const void* __restrict__ A1v,
    const u16* __restrict__ A2h,
    const u16* __restrict__ Wt,
    const float* __restrict__ bias,
    const float* __restrict__ dis,
    void* __restrict__ Cv, int M, int ntiles)
{
    constexpr int K = K1 + K2;
    constexpr int T = K >> 5;        // k-iterations (always even)
    constexpr int KCH = K >> 3;      // 16B chunks per column
    static_assert((T & 1) == 0, "T must be even");
    __shared__ __align__(16) u32 Wl[128 * (K >> 1)];

    const int tid = threadIdx.x;

    // ---- stage W once (source-indexed into swizzled slots) ----
    for (int i = tid; i < 128 * KCH; i += 768) {
        int c = i / KCH, ch = i % KCH;
        int phys = ch ^ (c & 7);
        uint4 v = *(const uint4*)(Wt + (size_t)c * K + ch * 8);
        *(uint4*)&Wl[c * (K >> 1) + phys * 4] = v;
    }
    __syncthreads();

    const int l = tid & 63;
    const int w = tid >> 6;          // wave 0..11
    const int g = l >> 4;            // k-octet 0..3
    const int lr = l & 15;

    for (int t = blockIdx.x * 12 + w; t < ntiles; t += gridDim.x * 12) {
        const int r0 = t * 32;
        int rlo = r0 + lr;       if (rlo >= M) rlo = M - 1;
        int rhi = r0 + 16 + lr;  if (rhi >= M) rhi = M - 1;

        const float* a1fl = (const float*)A1v + (size_t)rlo * K1 + g * 8;
        const float* a1fh = (const float*)A1v + (size_t)rhi * K1 + g * 8;
        const u16*   a1hl = (const u16*)A1v + (size_t)rlo * K1 + g * 8;
        const u16*   a1hh = (const u16*)A1v + (size_t)rhi * K1 + g * 8;
        const u16*   a2hl = A2h + (size_t)rlo * K2 + g * 8;
        const u16*   a2hh = A2h + (size_t)rhi * K2 + g * 8;

        f32x4 acc[2][8];
#pragma unroll
        for (int a = 0; a < 2; a++)
#pragma unroll
            for (int j = 0; j < 8; j++) acc[a][j] = (f32x4)0.f;

        u32 pkA[8], pkB[8];

        auto load_pk = [&](int i, u32* pk) {
            const int k0 = i * 32;
            if (K2 == 0 || k0 < K1) {
                if (A1BF) {
                    uint4 a = *(const uint4*)(a1hl + k0);
                    uint4 b = *(const uint4*)(a1hh + k0);
                    pk[0] = a.x; pk[1] = a.y; pk[2] = a.z; pk[3] = a.w;
                    pk[4] = b.x; pk[5] = b.y; pk[6] = b.z; pk[7] = b.w;
                } else {
                    const float* sl = a1fl + k0;
                    const float* sh2 = a1fh + k0;
                    float4 f0 = *(const float4*)(sl);
                    float4 f1 = *(const float4*)(sl + 4);
                    float4 f2 = *(const float4*)(sh2);
                    float4 f3 = *(const float4*)(sh2 + 4);
                    pk[0] = pack_bf16(f0.x, f0.y); pk[1] = pack_bf16(f0.z, f0.w);
                    pk[2] = pack_bf16(f1.x, f1.y); pk[3] = pack_bf16(f1.z, f1.w);
                    pk[4] = pack_bf16(f2.x, f2.y); pk[5] = pack_bf16(f2.z, f2.w);
                    pk[6] = pack_bf16(f3.x, f3.y); pk[7] = pack_bf16(f3.z, f3.w);
                }
            } else {
                uint4 a = *(const uint4*)(a2hl + (k0 - K1));
                uint4 b = *(const uint4*)(a2hh + (k0 - K1));
                pk[0] = a.x; pk[1] = a.y; pk[2] = a.z; pk[3] = a.w;
                pk[4] = b.x; pk[5] = b.y; pk[6] = b.z; pk[7] = b.w;
            }
        };

        auto compute = [&](int i, const u32* pk) {
            uint4 qa = make_uint4(pk[0], pk[1], pk[2], pk[3]);
            uint4 qb = make_uint4(pk[4], pk[5], pk[6], pk[7]);
            bf16x8 af0 = __builtin_bit_cast(bf16x8, qa);
            bf16x8 af1 = __builtin_bit_cast(bf16x8, qb);
            const int chb = i * 4 + g;
#pragma unroll
            for (int cb = 0; cb < 8; cb++) {
                int c = cb * 16 + lr;
                int phys = chb ^ (c & 7);
                bf16x8 bf = *(const bf16x8*)&Wl[c * (K >> 1) + phys * 4];
                acc[0][cb] = __builtin_amdgcn_mfma_f32_16x16x32_bf16(af0, bf, acc[0][cb], 0, 0, 0);
                acc[1][cb] = __builtin_amdgcn_mfma_f32_16x16x32_bf16(af1, bf, acc[1][cb], 0, 0, 0);
            }
        };

        load_pk(0, pkA);
#pragma unroll
        for (int i = 0; i < T; i += 2) {
            if (i + 1 < T) load_pk(i + 1, pkB);
            compute(i, pkA);
            if (i + 2 < T) load_pk(i + 2, pkA);
            compute(i + 1, pkB);
        }

        // ---- epilogue: acc[rf][cb][j] -> row = r0 + rf*16 + g*4 + j, col = cb*16+lr ----
        float disv[2][4];
        if (SCALE) {
#pragma unroll
            for (int rf = 0; rf < 2; rf++)
#pragma unroll
                for (int j = 0; j < 4; j++) {
                    int row = r0 + rf * 16 + g * 4 + j;
                    disv[rf][j] = (row < M) ? dis[row] : 0.f;
                }
        }
#pragma unroll
        for (int rf = 0; rf < 2; rf++) {
#pragma unroll
            for (int cb = 0; cb < 8; cb++) {
                int col = cb * 16 + lr;
                float bv = BIAS ? bias[col] : 0.f;
#pragma unroll
                for (int j = 0; j < 4; j++) {
                    int row = r0 + rf * 16 + g * 4 + j;
                    if (row < M) {
                        float v = acc[rf][cb][j];
                        if (BIAS) v += bv;
                        if (SCALE) v *= disv[rf][j];
                        if (RELU) v = fmaxf(v, 0.f);
                        if (OUT == 0) {
                            ((u16*)Cv)[(size_t)row * 128 + col] = pack1_bf16(v);
                        } else {
                            ((u8*)Cv)[(size_t)row * 128 + col] = pack1_fp8(v);
                        }
                    }
                }
            }
        }
    }
}

// ---------------- wave-split gather (fp8 in), 8-edge unroll ----------------
// Lanes 0-31 cover one edge's 128B row (u32 = 4 fp8/lane); lanes 32-63 the next.
// csr entries are pre-shifted word offsets (src*32).
// MODE 0: write bf16 h row. MODE 1: fused logits + log_softmax.

template<int MODE>
__global__ __launch_bounds__(256) void k_gatherw(
    const u32* __restrict__ xls32, const int* __restrict__ row_start,
    const int* __restrict__ csr, const float* __restrict__ dis,
    const float* __restrict__ bias, const float* __restrict__ Wl,
    const float* __restrict__ bl, void* __restrict__ outv, int N)
{
    int wave = threadIdx.x >> 6;
    int lane = threadIdx.x & 63;
    int half = lane >> 5;
    int w32 = lane & 31;
    int n = blockIdx.x * 4 + wave;
    if (n >= N) return;
    int jb = row_start[n], je = row_start[n + 1];

    float a0 = 0.f, a1 = 0.f, a2 = 0.f, a3 = 0.f;
    {
        u32 v = xls32[(u32)n * 32 + w32];   // self row
        if (half == 0) {
            f32x2 lo = __builtin_amdgcn_cvt_pk_f32_fp8((int)v, false);
            f32x2 hi = __builtin_amdgcn_cvt_pk_f32_fp8((int)v, true);
            a0 = lo.x; a1 = lo.y; a2 = hi.x; a3 = hi.y;
        }
    }

    int j = jb;
    for (; j + 7 < je; j += 8) {
        int c0 = csr[j + 4 * half + 0];
        int c1 = csr[j + 4 * half + 1];
        int c2 = csr[j + 4 * half + 2];
        int c3 = csr[j + 4 * half + 3];
        u32 v0 = xls32[(u32)c0 + w32];
        u32 v1 = xls32[(u32)c1 + w32];
        u32 v2 = xls32[(u32)c2 + w32];
        u32 v3 = xls32[(u32)c3 + w32];
        f32x2 l0 = __builtin_amdgcn_cvt_pk_f32_fp8((int)v0, false);
        f32x2 h0 = __builtin_amdgcn_cvt_pk_f32_fp8((int)v0, true);
        f32x2 l1 = __builtin_amdgcn_cvt_pk_f32_fp8((int)v1, false);
        f32x2 h1 = __builtin_amdgcn_cvt_pk_f32_fp8((int)v1, true);
        f32x2 l2 = __builtin_amdgcn_cvt_pk_f32_fp8((int)v2, false);
        f32x2 h2 = __builtin_amdgcn_cvt_pk_f32_fp8((int)v2, true);
        f32x2 l3 = __builtin_amdgcn_cvt_pk_f32_fp8((int)v3, false);
        f32x2 h3 = __builtin_amdgcn_cvt_pk_f32_fp8((int)v3, true);
        a0 += (l0.x + l1.x) + (l2.x + l3.x);
        a1 += (l0.y + l1.y) + (l2.y + l3.y);
        a2 += (h0.x + h1.x) + (h2.x + h3.x);
        a3 += (h0.y + h1.y) + (h2.y + h3.y);
    }
    for (; j + 3 < je; j += 4) {
        int c0 = csr[j + 2 * half];
        int c1 = csr[j + 2 * half + 1];
        u32 v0 = xls32[(u32)c0 + w32];
        u32 v1 = xls32[(u32)c1 + w32];
        f32x2 l0 = __builtin_amdgcn_cvt_pk_f32_fp8((int)v0, false);
        f32x2 h0 = __builtin_amdgcn_cvt_pk_f32_fp8((int)v0, true);
        f32x2 l1 = __builtin_amdgcn_cvt_pk_f32_fp8((int)v1, false);
        f32x2 h1 = __builtin_amdgcn_cvt_pk_f32_fp8((int)v1, true);
        a0 += l0.x + l1.x; a1 += l0.y + l1.y;
        a2 += h0.x + h1.x; a3 += h0.y + h1.y;
    }
    if (j + 1 < je) {
        int c = csr[j + half];
        u32 v = xls32[(u32)c + w32];
        f32x2 lo = __builtin_amdgcn_cvt_pk_f32_fp8((int)v, false);
        f32x2 hi = __builtin_amdgcn_cvt_pk_f32_fp8((int)v, true);
        a0 += lo.x; a1 += lo.y; a2 += hi.x; a3 += hi.y;
        j += 2;
    }
    if (j < je) {
        int c = csr[j];
        u32 v = xls32[(u32)c + w32];
        if (half == 0) {
            f32x2 lo = __builtin_amdgcn_cvt_pk_f32_fp8((int)v, false);
            f32x2 hi = __builtin_amdgcn_cvt_pk_f32_fp8((int)v, true);
            a0 += lo.x; a1 += lo.y; a2 += hi.x; a3 += hi.y;
        }
    }

    a0 += __shfl(a0, w32 + 32);
    a1 += __shfl(a1, w32 + 32);
    a2 += __shfl(a2, w32 + 32);
    a3 += __shfl(a3, w32 + 32);

    float d = dis[n];
    float4 bv = *(const float4*)&bias[w32 * 4];
    float h0v = fmaxf(fmaf(d, a0, bv.x), 0.f);
    float h1v = fmaxf(fmaf(d, a1, bv.y), 0.f);
    float h2v = fmaxf(fmaf(d, a2, bv.z), 0.f);
    float h3v = fmaxf(fmaf(d, a3, bv.w), 0.f);

    if (MODE == 0) {
        if (half == 0) {
            uint2 pw;
            pw.x = pack_bf16(h0v, h1v);
            pw.y = pack_bf16(h2v, h3v);
            *(uint2*)((u32*)outv + (size_t)n * 64 + w32 * 2) = pw;
        }
    } else {
        float4 q0 = *(const float4*)&Wl[w32 * 8];
        float4 q1 = *(const float4*)&Wl[w32 * 8 + 4];
        float p0 = h0v * q0.x + h1v * q0.z + h2v * q1.x + h3v * q1.z;
        float p1 = h0v * q0.y + h1v * q0.w + h2v * q1.y + h3v * q1.w;
#pragma unroll
        for (int off = 16; off > 0; off >>= 1) {
            p0 += __shfl_down(p0, off);
            p1 += __shfl_down(p1, off);
        }
        if (lane == 0) {
            float z0 = p0 + bl[0], z1 = p1 + bl[1];
            float m = fmaxf(z0, z1);
            float ls = m + logf(expf(z0 - m) + expf(z1 - m));
            float* out = (float*)outv;
            out[(size_t)n * 2 + 0] = z0 - ls;
            out[(size_t)n * 2 + 1] = z1 - ls;
        }
    }
}

// ---------------- launch ----------------

extern "C" void kernel_launch(void* const* d_in, const int* in_sizes, int n_in,
                              void* d_out, int out_size, void* d_ws, size_t ws_size,
                              hipStream_t stream) {
    const float* high  = (const float*)d_in[0];
    const float* low   = (const float*)d_in[1];
    const int*   ei    = (const int*)d_in[2];
    const float* W_emb = (const float*)d_in[3];
    const float* b_emb = (const float*)d_in[4];
    const float* W1    = (const float*)d_in[5];
    const float* b1    = (const float*)d_in[6];
    const float* W2    = (const float*)d_in[7];
    const float* b2    = (const float*)d_in[8];
    const float* Wl    = (const float*)d_in[9];
    const float* bl    = (const float*)d_in[10];

    int N = in_sizes[0] / HIGH;
    int E = in_sizes[2] / 2;
    const int* srcp = ei;
    const int* dstp = ei + E;
    float* out = (float*)d_out;

    int NB = (N + 255) >> BINSHIFT;
    int NSCAN = NB * NBLK;

    char* ws = (char*)d_ws;
    size_t off = 0;
    auto alloc = [&](size_t b) { size_t o = off; off += (b + 255) & ~(size_t)255; return o; };
    float* dis       = (float*)(ws + alloc((size_t)N * 4));
    int*   row_start = (int*)  (ws + alloc((size_t)(N + 1) * 4));
    int*   bsums     = (int*)  (ws + alloc(4096));
    int*   cnts      = (int*)  (ws + alloc((size_t)NSCAN * 4));
    u32*   packed    = (u32*)  (ws + alloc((size_t)E * 4));
    int*   csr       = (int*)  (ws + alloc((size_t)E * 4));
    u16*   Wt1       = (u16*)  (ws + alloc((size_t)512 * 128 * 2));
    u16*   Wt2       = (u16*)  (ws + alloc((size_t)128 * 128 * 2));
    u16*   WtE       = (u16*)  (ws + alloc((size_t)64 * 128 * 2));
    u16*   bufE      = (u16*)  (ws + alloc((size_t)N * 128 * 2));  // bf16 low_emb
    u8*    bufX      = (u8*)   (ws + alloc((size_t)N * 128));      // fp8 xls
    u16*   bufH      = (u16*)  (ws + alloc((size_t)N * 128 * 2));  // bf16 h1
    (void)ws_size; (void)n_in; (void)out_size;

    int nbS = (NSCAN + 1023) / 1024;
    int ntiles = (N + 31) / 32;

    // ---- weight transpose+cast (one kernel) ----
    k_castw_all<<<(90112 + 255) / 256, 256, 0, stream>>>(W1, Wt1, W2, Wt2, W_emb, WtE);

    // ---- binned CSR build ----
    k_binhist<<<NBLK, 256, 0, stream>>>(dstp, E, cnts, NB);
    k_scan1<<<nbS, 256, 0, stream>>>(cnts, NSCAN, bsums);
    k_scan2<<<1, 64, 0, stream>>>(bsums, nbS);
    k_scan3_flat<<<nbS, 256, 0, stream>>>(cnts, NSCAN, bsums);
    k_binscatter<<<NBLK, 256, 0, stream>>>(srcp, dstp, E, cnts, packed, NB);
    k_csrbin<<<NB, 256, 0, stream>>>(packed, cnts, E, row_start, dis, csr, NB, N);

    // ---- network ----
    // low_emb = relu(low @ W_emb + b_emb)                 -> bufE (bf16)
    k_pgemm<LOWD, 0, false, true, true, false, 0><<<256, 768, 0, stream>>>(
        low, nullptr, WtE, b_emb, nullptr, bufE, N, ntiles);
    // xls1 = ([high | low_emb] @ W1) * dis                -> bufX (fp8)
    k_pgemm<HIGH, EMB, false, false, false, true, 1><<<256, 768, 0, stream>>>(
        high, bufE, Wt1, nullptr, dis, bufX, N, ntiles);
    // h1 = relu(dis * (gather(xls1) + self) + b1)         -> bufH (bf16)
    k_gatherw<0><<<(N + 3) / 4, 256, 0, stream>>>(
        (const u32*)bufX, row_start, csr, dis, b1, nullptr, nullptr, bufH, N);
    // xls2 = (h1 @ W2) * dis                              -> bufX (fp8)
    k_pgemm<HID, 0, true, false, false, true, 1><<<256, 768, 0, stream>>>(
        bufH, nullptr, Wt2, nullptr, dis, bufX, N, ntiles);
    // out = log_softmax((dis * (gather(xls2) + self) + b2) @ W_lin + b_lin)  [fused]
    k_gatherw<1><<<(N + 3) / 4, 256, 0, stream>>>(
        (const u32*)bufX, row_start, csr, dis, b2, Wl, bl, out, N);
}

// Round 13
// 351.069 us; speedup vs baseline: 1.7814x; 1.7814x over previous
//
#include <hip/hip_runtime.h>

#define HIGH 384
#define LOWD 64
#define EMB  128
#define HID  128

// Binned CSR build: bin = dst >> 8. Requires N <= 131072 (src packs in 17 bits).
#define BINSHIFT 8
#define SRCBITS  17
#define SRCMASK  0x1FFFF
#define NBLK     256

typedef unsigned int u32;
typedef unsigned short u16;
typedef unsigned char u8;
typedef __attribute__((ext_vector_type(8))) short bf16x8;
typedef __attribute__((ext_vector_type(4))) float f32x4;
typedef __attribute__((ext_vector_type(2))) float f32x2;

__device__ __forceinline__ u32 pack_bf16(float a, float b) {
    u32 ua = __builtin_bit_cast(u32, a);
    u32 ub = __builtin_bit_cast(u32, b);
    ua += 0x7fffu + ((ua >> 16) & 1u);
    ub += 0x7fffu + ((ub >> 16) & 1u);
    return (ua >> 16) | (ub & 0xffff0000u);
}
__device__ __forceinline__ u16 pack1_bf16(float a) {
    u32 ua = __builtin_bit_cast(u32, a);
    ua += 0x7fffu + ((ua >> 16) & 1u);
    return (u16)(ua >> 16);
}
__device__ __forceinline__ u8 pack1_fp8(float a) {
    int r = __builtin_amdgcn_cvt_pk_fp8_f32(a, a, 0, false);
    return (u8)(r & 0xff);
}

// ---------------- utility kernels ----------------

// All three weights: W[K][128] fp32 -> Wt[128][K] bf16
__global__ void k_castw_all(const float* __restrict__ W1, u16* __restrict__ Wt1,
                            const float* __restrict__ W2, u16* __restrict__ Wt2,
                            const float* __restrict__ WE, u16* __restrict__ WtE) {
    int i = blockIdx.x * 256 + threadIdx.x;
    if (i < 65536) {                       // W1: K=512
        int k = i >> 7, c = i & 127;
        Wt1[c * 512 + k] = pack1_bf16(W1[i]);
    } else if (i < 81920) {                // W2: K=128
        int j = i - 65536;
        int k = j >> 7, c = j & 127;
        Wt2[c * 128 + k] = pack1_bf16(W2[j]);
    } else if (i < 90112) {                // W_emb: K=64
        int j = i - 81920;
        int k = j >> 7, c = j & 127;
        WtE[c * 64 + k] = pack1_bf16(WE[j]);
    }
}

// ---------------- binned edge partition ----------------

__global__ __launch_bounds__(256) void k_binhist(const int* __restrict__ dst, int E,
                                                 int* __restrict__ cnts, int NB) {
    __shared__ int hist[512];
    for (int b = threadIdx.x; b < NB; b += 256) hist[b] = 0;
    __syncthreads();
    int CH = (E + gridDim.x - 1) / gridDim.x;
    int e0 = blockIdx.x * CH;
    int e1 = min(E, e0 + CH);
    for (int e = e0 + threadIdx.x; e < e1; e += 256)
        atomicAdd(&hist[dst[e] >> BINSHIFT], 1);
    __syncthreads();
    for (int b = threadIdx.x; b < NB; b += 256)
        cnts[b * NBLK + blockIdx.x] = hist[b];
}

__global__ __launch_bounds__(256) void k_binscatter(const int* __restrict__ src,
                                                    const int* __restrict__ dst, int E,
                                                    const int* __restrict__ cnts,
                                                    u32* __restrict__ packed, int NB) {
    __shared__ int cur[512];
    for (int b = threadIdx.x; b < NB; b += 256) cur[b] = cnts[b * NBLK + blockIdx.x];
    __syncthreads();
    int CH = (E + gridDim.x - 1) / gridDim.x;
    int e0 = blockIdx.x * CH;
    int e1 = min(E, e0 + CH);
    for (int e = e0 + threadIdx.x; e < e1; e += 256) {
        int d = dst[e];
        int s = src[e];
        int bin = d >> BINSHIFT;
        int pos = atomicAdd(&cur[bin], 1);
        packed[pos] = (u32)s | ((u32)(d & 255) << SRCBITS);
    }
}

// Fused per-bin CSR finalize: degree hist -> prefix -> row_start + dis -> csr fill.
__global__ __launch_bounds__(256) void k_csrbin(
    const u32* __restrict__ packed, const int* __restrict__ cnts, int E,
    int* __restrict__ row_start, float* __restrict__ dis,
    int* __restrict__ csr, int NB, int N)
{
    __shared__ int hist[256];
    __shared__ int sc[256];
    int t = threadIdx.x;
    int b = blockIdx.x;
    int begin = cnts[b * NBLK];
    int end = (b + 1 < NB) ? cnts[(b + 1) * NBLK] : E;

    hist[t] = 0;
    __syncthreads();
    for (int e = begin + t; e < end; e += 256)
        atomicAdd(&hist[packed[e] >> SRCBITS], 1);
    __syncthreads();
    int deg = hist[t];

    sc[t] = deg;
    __syncthreads();
    int x = deg;
    for (int off = 1; off < 256; off <<= 1) {
        int y = (t >= off) ? sc[t - off] : 0;
        __syncthreads();
        x += y; sc[t] = x;
        __syncthreads();
    }
    int rs = begin + (x - deg);

    int node = (b << BINSHIFT) + t;
    if (node < N) {
        row_start[node] = rs;
        dis[node] = rsqrtf((float)deg + 1.0f);
    }
    if (b == NB - 1 && t == 0) row_start[N] = E;

    hist[t] = rs;
    __syncthreads();
    for (int e = begin + t; e < end; e += 256) {
        u32 p = packed[e];
        int pos = atomicAdd(&hist[p >> SRCBITS], 1);
        csr[pos] = (int)((p & SRCMASK) << 5);
    }
}

// ---------------- scan (3-kernel, for cnts only) ----------------

__global__ void k_scan1(const int* __restrict__ in, int n, int* __restrict__ bsums) {
    __shared__ int sh[256];
    int t = threadIdx.x;
    int base = blockIdx.x * 1024 + t * 4;
    int s = 0;
#pragma unroll
    for (int j = 0; j < 4; j++) { int idx = base + j; s += (idx < n) ? in[idx] : 0; }
    sh[t] = s; __syncthreads();
    for (int off = 128; off > 0; off >>= 1) {
        if (t < off) sh[t] += sh[t + off];
        __syncthreads();
    }
    if (t == 0) bsums[blockIdx.x] = sh[0];
}

__global__ void k_scan2(int* bsums, int nb) {
    if (threadIdx.x == 0 && blockIdx.x == 0) {
        int run = 0;
        for (int i = 0; i < nb; i++) { int v = bsums[i]; bsums[i] = run; run += v; }
    }
}

__global__ void k_scan3_flat(int* __restrict__ data, int n, const int* __restrict__ bsums) {
    __shared__ int sh[256];
    int t = threadIdx.x;
    int base = blockIdx.x * 1024 + t * 4;
    int v[4]; int s = 0;
#pragma unroll
    for (int j = 0; j < 4; j++) { int idx = base + j; v[j] = (idx < n) ? data[idx] : 0; s += v[j]; }
    sh[t] = s; __syncthreads();
    int x = s;
    for (int off = 1; off < 256; off <<= 1) {
        int y = (t >= off) ? sh[t - off] : 0;
        __syncthreads();
        x += y; sh[t] = x;
        __syncthreads();
    }
    int run = bsums[blockIdx.x] + (x - s);
#pragma unroll
    for (int j = 0; j < 4; j++) {
        int idx = base + j;
        if (idx < n) data[idx] = run;
        run += v[j];
    }
}

// ---------------- MFMA GEMM (R8 schedule, best known): C = [A1|A2] @ W ----
// BM=64, BN=128, BK=32, 256 threads (4 waves), wave tile 16x128 (1x8 frags 16x16x32).
// OUT: 0 = bf16 row (256B), 1 = fp8 e4m3 row (128B).

template<bool A1BF, bool BIAS, bool RELU, bool SCALE, int OUT>
__global__ __launch_bounds__(256, 6) void k_mgemm(
    const void* __restrict__ A1v, int K1,
    const u32* __restrict__ A2, int K2,
    const u16* __restrict__ Wt,
    const float* __restrict__ bias,
    const float* __restrict__ dis,
    void* __restrict__ Cv, int M)
{
    __shared__ u32 Als[2][64][16];
    __shared__ u32 Bls[2][128][16];

    const int tid = threadIdx.x;
    const int l = tid & 63;
    const int w = tid >> 6;
    const int g = l >> 4;      // k-group 0..3
    const int lr = l & 15;
    const int blockRow = blockIdx.x * 64;
    const int K = K1 + K2;
    const int T = K >> 5;

    const int ar = tid >> 2;        // 0..63
    const int ak = tid & 3;         // k-block
    int arow = blockRow + ar; if (arow >= M) arow = M - 1;
    const int awb = (ak + ((ar >> 1) & 3)) & 3;       // swizzled write block

    const int wc = tid >> 1;        // 0..127 col
    const int wh = tid & 1;
    const int wsw = (wc >> 1) & 3;
    const int wb0 = (wh * 2 + wsw) & 3;
    const int wb1 = (wh * 2 + 1 + wsw) & 3;

    const float* a1f = (const float*)A1v + (size_t)arow * K1;
    const u32*   a1b = (const u32*)A1v + (size_t)arow * (K1 >> 1);
    const u32*   a2b = A2 + (size_t)arow * (K2 >> 1);
    const u32*   wtb = (const u32*)Wt + (size_t)wc * (K >> 1);

    f32x4 acc[8];
#pragma unroll
    for (int j = 0; j < 8; j++) acc[j] = (f32x4)0.f;

    u32 pa[4], wk[8];

    auto load_tile = [&](int k0) {
        if (k0 < K1) {
            if (A1BF) {
                uint4 a = *(const uint4*)(a1b + (k0 >> 1) + ak * 4);
                pa[0] = a.x; pa[1] = a.y; pa[2] = a.z; pa[3] = a.w;
            } else {
                const float* src = a1f + k0 + ak * 8;
                float4 f0 = *(const float4*)(src + 0);
                float4 f1 = *(const float4*)(src + 4);
                pa[0] = pack_bf16(f0.x, f0.y); pa[1] = pack_bf16(f0.z, f0.w);
                pa[2] = pack_bf16(f1.x, f1.y); pa[3] = pack_bf16(f1.z, f1.w);
            }
        } else {
            uint4 a = *(const uint4*)(a2b + ((k0 - K1) >> 1) + ak * 4);
            pa[0] = a.x; pa[1] = a.y; pa[2] = a.z; pa[3] = a.w;
        }
        const u32* srcw = wtb + ((k0 + wh * 16) >> 1);
        uint4 a = *(const uint4*)srcw;
        uint4 b = *(const uint4*)(srcw + 4);
        wk[0] = a.x; wk[1] = a.y; wk[2] = a.z; wk[3] = a.w;
        wk[4] = b.x; wk[5] = b.y; wk[6] = b.z; wk[7] = b.w;
    };
    auto store_tile = [&](int buf) {
        *(uint4*)&Als[buf][ar][awb * 4] = make_uint4(pa[0], pa[1], pa[2], pa[3]);
        *(uint4*)&Bls[buf][wc][wb0 * 4] = make_uint4(wk[0], wk[1], wk[2], wk[3]);
        *(uint4*)&Bls[buf][wc][wb1 * 4] = make_uint4(wk[4], wk[5], wk[6], wk[7]);
    };

    load_tile(0);
    store_tile(0);
    __syncthreads();

    for (int t = 0; t < T; t++) {
        const int cur = t & 1;
        const bool more = (t + 1 < T);
        if (more) load_tile((t + 1) << 5);   // issue global loads early

        bf16x8 af;
        {
            int r = w * 16 + lr;
            int blk = (g + ((r >> 1) & 3)) & 3;
            af = *(const bf16x8*)&Als[cur][r][blk * 4];
        }
#pragma unroll
        for (int cb = 0; cb < 8; cb++) {
            int c = cb * 16 + lr;
            int blk = (g + ((c >> 1) & 3)) & 3;
            bf16x8 bf = *(const bf16x8*)&Bls[cur][c][blk * 4];
            acc[cb] = __builtin_amdgcn_mfma_f32_16x16x32_bf16(af, bf, acc[cb], 0, 0, 0);
        }
        if (more) store_tile(cur ^ 1);       // write late
        __syncthreads();
    }

    // ---- epilogue ----
    float disv[4];
    if (SCALE) {
#pragma unroll
        for (int j = 0; j < 4; j++) {
            int row = blockRow + w * 16 + g * 4 + j;
            disv[j] = (row < M) ? dis[row] : 0.f;
        }
    }
#pragma unroll
    for (int cb = 0; cb < 8; cb++) {
        int col = cb * 16 + lr;
        float bv = BIAS ? bias[col] : 0.f;
#pragma unroll
        for (int j = 0; j < 4; j++) {
            int row = blockRow + w * 16 + g * 4 + j;
            if (row < M) {
                float v = acc[cb][j];
                if (BIAS) v += bv;
                if (SCALE) v *= disv[j];
                if (RELU) v = fmaxf(v, 0.f);
                if (OUT == 0) {
                    ((u16*)Cv)[(size_t)row * 128 + col] = pack1_bf16(v);
                } else {
                    ((u8*)Cv)[(size_t)row * 128 + col] = pack1_fp8(v);
                }
            }
        }
    }
}

// ---------------- wave-split gather (fp8 in), 8-edge unroll ----------------
// Lanes 0-31 cover one edge's 128B row (u32 = 4 fp8/lane); lanes 32-63 the next.
// csr entries are pre-shifted word offsets (src*32).
// MODE 0: write bf16 h row. MODE 1: fused logits + log_softmax.

template<int MODE>
__global__ __launch_bounds__(256) void k_gatherw(
    const u32* __restrict__ xls32, const int* __restrict__ row_start,
    const int* __restrict__ csr, const float* __restrict__ dis,
    const float* __restrict__ bias, const float* __restrict__ Wl,
    const float* __restrict__ bl, void* __restrict__ outv, int N)
{
    int wave = threadIdx.x >> 6;
    int lane = threadIdx.x & 63;
    int half = lane >> 5;
    int w32 = lane & 31;
    int n = blockIdx.x * 4 + wave;
    if (n >= N) return;
    int jb = row_start[n], je = row_start[n + 1];

    float a0 = 0.f, a1 = 0.f, a2 = 0.f, a3 = 0.f;
    {
        u32 v = xls32[(u32)n * 32 + w32];   // self row
        if (half == 0) {
            f32x2 lo = __builtin_amdgcn_cvt_pk_f32_fp8((int)v, false);
            f32x2 hi = __builtin_amdgcn_cvt_pk_f32_fp8((int)v, true);
            a0 = lo.x; a1 = lo.y; a2 = hi.x; a3 = hi.y;
        }
    }

    int j = jb;
    for (; j + 7 < je; j += 8) {
        int c0 = csr[j + 4 * half + 0];
        int c1 = csr[j + 4 * half + 1];
        int c2 = csr[j + 4 * half + 2];
        int c3 = csr[j + 4 * half + 3];
        u32 v0 = xls32[(u32)c0 + w32];
        u32 v1 = xls32[(u32)c1 + w32];
        u32 v2 = xls32[(u32)c2 + w32];
        u32 v3 = xls32[(u32)c3 + w32];
        f32x2 l0 = __builtin_amdgcn_cvt_pk_f32_fp8((int)v0, false);
        f32x2 h0 = __builtin_amdgcn_cvt_pk_f32_fp8((int)v0, true);
        f32x2 l1 = __builtin_amdgcn_cvt_pk_f32_fp8((int)v1, false);
        f32x2 h1 = __builtin_amdgcn_cvt_pk_f32_fp8((int)v1, true);
        f32x2 l2 = __builtin_amdgcn_cvt_pk_f32_fp8((int)v2, false);
        f32x2 h2 = __builtin_amdgcn_cvt_pk_f32_fp8((int)v2, true);
        f32x2 l3 = __builtin_amdgcn_cvt_pk_f32_fp8((int)v3, false);
        f32x2 h3 = __builtin_amdgcn_cvt_pk_f32_fp8((int)v3, true);
        a0 += (l0.x + l1.x) + (l2.x + l3.x);
        a1 += (l0.y + l1.y) + (l2.y + l3.y);
        a2 += (h0.x + h1.x) + (h2.x + h3.x);
        a3 += (h0.y + h1.y) + (h2.y + h3.y);
    }
    for (; j + 3 < je; j += 4) {
        int c0 = csr[j + 2 * half];
        int c1 = csr[j + 2 * half + 1];
        u32 v0 = xls32[(u32)c0 + w32];
        u32 v1 = xls32[(u32)c1 + w32];
        f32x2 l0 = __builtin_amdgcn_cvt_pk_f32_fp8((int)v0, false);
        f32x2 h0 = __builtin_amdgcn_cvt_pk_f32_fp8((int)v0, true);
        f32x2 l1 = __builtin_amdgcn_cvt_pk_f32_fp8((int)v1, false);
        f32x2 h1 = __builtin_amdgcn_cvt_pk_f32_fp8((int)v1, true);
        a0 += l0.x + l1.x; a1 += l0.y + l1.y;
        a2 += h0.x + h1.x; a3 += h0.y + h1.y;
    }
    if (j + 1 < je) {
        int c = csr[j + half];
        u32 v = xls32[(u32)c + w32];
        f32x2 lo = __builtin_amdgcn_cvt_pk_f32_fp8((int)v, false);
        f32x2 hi = __builtin_amdgcn_cvt_pk_f32_fp8((int)v, true);
        a0 += lo.x; a1 += lo.y; a2 += hi.x; a3 += hi.y;
        j += 2;
    }
    if (j < je) {
        int c = csr[j];
        u32 v = xls32[(u32)c + w32];
        if (half == 0) {
            f32x2 lo = __builtin_amdgcn_cvt_pk_f32_fp8((int)v, false);
            f32x2 hi = __builtin_amdgcn_cvt_pk_f32_fp8((int)v, true);
            a0 += lo.x; a1 += lo.y; a2 += hi.x; a3 += hi.y;
        }
    }

    a0 += __shfl(a0, w32 + 32);
    a1 += __shfl(a1, w32 + 32);
    a2 += __shfl(a2, w32 + 32);
    a3 += __shfl(a3, w32 + 32);

    float d = dis[n];
    float4 bv = *(const float4*)&bias[w32 * 4];
    float h0v = fmaxf(fmaf(d, a0, bv.x), 0.f);
    float h1v = fmaxf(fmaf(d, a1, bv.y), 0.f);
    float h2v = fmaxf(fmaf(d, a2, bv.z), 0.f);
    float h3v = fmaxf(fmaf(d, a3, bv.w), 0.f);

    if (MODE == 0) {
        if (half == 0) {
            uint2 pw;
            pw.x = pack_bf16(h0v, h1v);
            pw.y = pack_bf16(h2v, h3v);
            *(uint2*)((u32*)outv + (size_t)n * 64 + w32 * 2) = pw;
        }
    } else {
        float4 q0 = *(const float4*)&Wl[w32 * 8];
        float4 q1 = *(const float4*)&Wl[w32 * 8 + 4];
        float p0 = h0v * q0.x + h1v * q0.z + h2v * q1.x + h3v * q1.z;
        float p1 = h0v * q0.y + h1v * q0.w + h2v * q1.y + h3v * q1.w;
#pragma unroll
        for (int off = 16; off > 0; off >>= 1) {
            p0 += __shfl_down(p0, off);
            p1 += __shfl_down(p1, off);
        }
        if (lane == 0) {
            float z0 = p0 + bl[0], z1 = p1 + bl[1];
            float m = fmaxf(z0, z1);
            float ls = m + logf(expf(z0 - m) + expf(z1 - m));
            float* out = (float*)outv;
            out[(size_t)n * 2 + 0] = z0 - ls;
            out[(size_t)n * 2 + 1] = z1 - ls;
        }
    }
}

// ---------------- launch ----------------

extern "C" void kernel_launch(void* const* d_in, const int* in_sizes, int n_in,
                              void* d_out, int out_size, void* d_ws, size_t ws_size,
                              hipStream_t stream) {
    const float* high  = (const float*)d_in[0];
    const float* low   = (const float*)d_in[1];
    const int*   ei    = (const int*)d_in[2];
    const float* W_emb = (const float*)d_in[3];
    const float* b_emb = (const float*)d_in[4];
    const float* W1    = (const float*)d_in[5];
    const float* b1    = (const float*)d_in[6];
    const float* W2    = (const float*)d_in[7];
    const float* b2    = (const float*)d_in[8];
    const float* Wl    = (const float*)d_in[9];
    const float* bl    = (const float*)d_in[10];

    int N = in_sizes[0] / HIGH;
    int E = in_sizes[2] / 2;
    const int* srcp = ei;
    const int* dstp = ei + E;
    float* out = (float*)d_out;

    int NB = (N + 255) >> BINSHIFT;
    int NSCAN = NB * NBLK;

    char* ws = (char*)d_ws;
    size_t off = 0;
    auto alloc = [&](size_t b) { size_t o = off; off += (b + 255) & ~(size_t)255; return o; };
    float* dis       = (float*)(ws + alloc((size_t)N * 4));
    int*   row_start = (int*)  (ws + alloc((size_t)(N + 1) * 4));
    int*   bsums     = (int*)  (ws + alloc(4096));
    int*   cnts      = (int*)  (ws + alloc((size_t)NSCAN * 4));
    u32*   packed    = (u32*)  (ws + alloc((size_t)E * 4));
    int*   csr       = (int*)  (ws + alloc((size_t)E * 4));
    u16*   Wt1       = (u16*)  (ws + alloc((size_t)512 * 128 * 2));
    u16*   Wt2       = (u16*)  (ws + alloc((size_t)128 * 128 * 2));
    u16*   WtE       = (u16*)  (ws + alloc((size_t)64 * 128 * 2));
    u16*   bufE      = (u16*)  (ws + alloc((size_t)N * 128 * 2));  // bf16 low_emb
    u8*    bufX      = (u8*)   (ws + alloc((size_t)N * 128));      // fp8 xls
    u16*   bufH      = (u16*)  (ws + alloc((size_t)N * 128 * 2));  // bf16 h1
    (void)ws_size; (void)n_in; (void)out_size;

    int nbS = (NSCAN + 1023) / 1024;
    int mt  = (N + 63) / 64;

    // ---- weight transpose+cast (one kernel) ----
    k_castw_all<<<(90112 + 255) / 256, 256, 0, stream>>>(W1, Wt1, W2, Wt2, W_emb, WtE);

    // ---- binned CSR build ----
    k_binhist<<<NBLK, 256, 0, stream>>>(dstp, E, cnts, NB);
    k_scan1<<<nbS, 256, 0, stream>>>(cnts, NSCAN, bsums);
    k_scan2<<<1, 64, 0, stream>>>(bsums, nbS);
    k_scan3_flat<<<nbS, 256, 0, stream>>>(cnts, NSCAN, bsums);
    k_binscatter<<<NBLK, 256, 0, stream>>>(srcp, dstp, E, cnts, packed, NB);
    k_csrbin<<<NB, 256, 0, stream>>>(packed, cnts, E, row_start, dis, csr, NB, N);

    // ---- network ----
    // low_emb = relu(low @ W_emb + b_emb)                 -> bufE (bf16)
    k_mgemm<false, true, true, false, 0><<<mt, 256, 0, stream>>>(
        low, LOWD, (const u32*)bufE, 0, WtE, b_emb, nullptr, bufE, N);
    // xls1 = ([high | low_emb] @ W1) * dis                -> bufX (fp8)
    k_mgemm<false, false, false, true, 1><<<mt, 256, 0, stream>>>(
        high, HIGH, (const u32*)bufE, EMB, Wt1, nullptr, dis, bufX, N);
    // h1 = relu(dis * (gather(xls1) + self) + b1)         -> bufH (bf16)
    k_gatherw<0><<<(N + 3) / 4, 256, 0, stream>>>(
        (const u32*)bufX, row_start, csr, dis, b1, nullptr, nullptr, bufH, N);
    // xls2 = (h1 @ W2) * dis                              -> bufX (fp8)
    k_mgemm<true, false, false, true, 1><<<mt, 256, 0, stream>>>(
        bufH, HID, (const u32*)bufH, 0, Wt2, nullptr, dis, bufX, N);
    // out = log_softmax((dis * (gather(xls2) + self) + b2) @ W_lin + b_lin)  [fused]
    k_gatherw<1><<<(N + 3) / 4, 256, 0, stream>>>(
        (const u32*)bufX, row_start, csr, dis, b2, Wl, bl, out, N);
}